// Round 17
// baseline (471.833 us; speedup 1.0000x reference)
//
#include <hip/hip_runtime.h>
#include <hip/hip_bf16.h>
#include <stdint.h>

#define BATCH 128
#define SEQ   512
#define NW    6
#define DIM   64
#define NELEM (BATCH * SEQ * NW)   // 393216
#define PI_F  3.14159265358979323846f
#define NCONV 1536                 // convert blocks; msetup blocks follow

typedef float v2f __attribute__((ext_vector_type(2)));

__device__ __forceinline__ v2f pkfma(float s, v2f m, v2f a) {
    return __builtin_elementwise_fma((v2f){s, s}, m, a);
}

// ---------------------------------------------------------------------------
// Interleaved 3-way DPP wave-64 reduction stage. After shr1,2,4,8 +
// bcast15,31 the totals land in lane 63.
// ---------------------------------------------------------------------------
template <int CTRL>
__device__ __forceinline__ void red_stage3(float v[3]) {
#pragma unroll
    for (int k = 0; k < 3; ++k)
        v[k] += __int_as_float(__builtin_amdgcn_update_dpp(
            0, __float_as_int(v[k]), CTRL, 0xF, 0xF, false));
}

// Branch-free sincos(h/2), |h| <= 1 (bf16-output tolerance).
__device__ __forceinline__ void sincos_half(float h, float& s, float& c) {
    const float u = h * h;
    c = fmaf(u, fmaf(u, 2.6041667e-3f, -0.125f), 1.0f);
    s = h * fmaf(u, fmaf(u, 2.6041667e-4f, -2.0833333e-2f), 0.5f);
}

__device__ __forceinline__ float ldf(const void* p, int i, bool bf) {
    if (bf) {
        uint32_t u = (uint32_t)((const uint16_t*)p)[i];
        return __uint_as_float(u << 16);
    }
    return ((const float*)p)[i];
}

// ---------------------------------------------------------------------------
// Kernel 1 (fused detect + convert + msetup), identical to the r13-best:
//  - blocks [0,NCONV): cs[i] = {cos,sin}(x_i); misc fills; flag post
//  - blocks [NCONV, NCONV+32): each wave evolves one (dir,col) basis column
// ---------------------------------------------------------------------------
__global__ void k_prep(const void* ang, const void* poly, const void* fp,
                       const void* bp, const void* fc, const void* bc,
                       float* __restrict__ cs, float* __restrict__ misc,
                       float* __restrict__ Mg, int* __restrict__ flag) {
    __shared__ int cnt;
    if (threadIdx.x == 0) cnt = 0;
    __syncthreads();
    {
        uint32_t w = ((const uint32_t*)ang)[threadIdx.x & 255];
        uint32_t e = (w >> 8) & 0xFFu;
        if (e >= 0x3Au && e <= 0x41u) atomicAdd(&cnt, 1);
    }
    __syncthreads();
    const bool bf = (cnt >= 128);

    if (blockIdx.x < NCONV) {
        const int i = blockIdx.x * 256 + threadIdx.x;
        if (i < NELEM) {
            float x = ldf(ang, i, bf);
            float s, c;
            __sincosf(x, &s, &c);
            cs[2 * i]     = c;
            cs[2 * i + 1] = s;
        }
        if (i == 200)      misc[76] = ldf(fc, 0, bf);
        else if (i == 201) misc[77] = ldf(bc, 0, bf);
        else if (i == 202) *flag = bf ? 1 : 0;
        return;
    }

    // ---- msetup path: 4 columns per block (one per wave) ----
    const int lane = threadIdx.x & 63;
    const int tix  = (blockIdx.x - NCONV) * 4 + (threadIdx.x >> 6);
    const int dir  = tix >> 6;
    const int col  = tix & 63;
    const void* prm = dir ? bp : fp;
    const int p = lane;

    float yr = (p == col) ? 1.f : 0.f;
    float yi = 0.f;

#pragma unroll
    for (int d = 0; d < 4; ++d) {
        const float th = 0.5f * PI_F * ldf(poly, d, bf) *
                         (float)(6 - 2 * (int)__popc((unsigned)p));
        float s, c;
        __sincosf(th, &s, &c);
        const float nr = yr * c + yi * s;
        const float ni = yi * c - yr * s;
        yr = nr; yi = ni;
#pragma unroll
        for (int k = 0; k < 6; ++k) {
            const int cw = k, tw = (k + 1) % 6;
            const int src = p ^ (((p >> (5 - cw)) & 1) << (5 - tw));
            yr = __shfl(yr, src, 64);
            yi = __shfl(yi, src, 64);
        }
    }

    int idx = 0;
#pragma unroll
    for (int l = 0; l < 2; ++l) {
#pragma unroll
        for (int w = 0; w < 6; ++w) {
            float cx, sx, cy, sy, cz, sz;
            __sincosf(0.5f * ldf(prm, idx + 0, bf), &sx, &cx);
            __sincosf(0.5f * ldf(prm, idx + 1, bf), &sy, &cy);
            __sincosf(0.5f * ldf(prm, idx + 2, bf), &sz, &cz);
            idx += 3;
            const float A = cy * cx, B = sy * sx, C = sy * cx, D = cy * sx;
            const float U00r = cz * A + sz * B, U00i = cz * B - sz * A;
            const float U11r = U00r,            U11i = sz * A - cz * B;
            const float Xr   = cz * C + sz * D, Xi   = sz * C - cz * D;
            const int m  = 1 << (5 - w);
            const int bb = (p >> (5 - w)) & 1;
            const float C1r = bb ? U11r : U00r;
            const float C1i = bb ? U11i : U00i;
            const float C2r = bb ? Xr : -Xr;
            const float C2i = Xi;
            const float pr = __shfl_xor(yr, m, 64);
            const float pi = __shfl_xor(yi, m, 64);
            const float nr = C1r * yr - C1i * yi + C2r * pr - C2i * pi;
            const float ni = C1r * yi + C1i * yr + C2r * pi + C2i * pr;
            yr = nr; yi = ni;
        }
#pragma unroll
        for (int k = 0; k < 5; ++k) {
            const int src = p ^ (((p >> (5 - k)) & 1) << (5 - (k + 1)));
            yr = __shfl(yr, src, 64);
            yi = __shfl(yi, src, 64);
        }
    }

    float* out = Mg + ((size_t)(dir * 64 + p) * 64 + (size_t)col) * 2;
    out[0] = yr;
    out[1] = yi;
}

// ---------------------------------------------------------------------------
// Kernel 2: recurrent sim — exactly the r13-best structure (4 waves, split
// measurement, 6-bpermute X fetch, cs-staged cl), with ONE change: both
// per-step s_barriers are replaced by LDS EPOCH-FLAG rendezvous.
//   post:  lane0 release-stores its wave's epoch after the data writes
//          (release => lgkmcnt drain covers the whole wave's DS writes)
//   wait:  all lanes acquire-poll the other 3 waves' flags (uniform-address
//          broadcast reads). Same ordering invariants as the barrier
//          version: pY ping-pong + A/B epoch ordering keep single-buffered
//          mR race-free.
// ---------------------------------------------------------------------------
__global__ void __launch_bounds__(256, 1) k_sim(const float* __restrict__ cs,
                                                const float* __restrict__ Mg,
                                                float* __restrict__ hbuf) {
    const int tid   = threadIdx.x;
    const int lane  = tid & 63;
    const int wv    = tid >> 6;              // wave 0..3
    const int chain = blockIdx.x;            // 0..255
    const int dir   = chain >> 7;
    const int b     = chain & 127;
    float* orow = hbuf + (size_t)dir * NELEM + (size_t)b * (SEQ * NW);
    const float* csrow = cs + (size_t)b * (SEQ * NW * 2);

    __shared__ __align__(16) float  cl[SEQ * 12];   // 24 KB staged cos/sin(x)
    __shared__ __align__(16) float  zb[SEQ * NW];   // 12 KB output buffer
    __shared__ float2 pY[2][4][DIM];                // ping-pong partials, 4 KB
    __shared__ __align__(16) float  mR[12];         // measure-sum slab
    __shared__ int fA[4], fB[4];                    // epoch flags

    // ---- stage this chain's cos/sin rows into LDS (once) ----
    {
        const float4* src = (const float4*)csrow;   // 1536 float4
        float4* dst = (float4*)cl;
#pragma unroll
        for (int k = 0; k < 6; ++k) {
            const int idx = tid + k * 256;
            dst[idx] = src[idx];
        }
    }
    if (tid < 4) { fA[tid] = -1; fB[tid] = -1; }

    // ---- my 16 resident M columns: row = lane, cols = 16wv..16wv+15 ----
    v2f Mres[16];
    {
        const float2* mr2 =
            (const float2*)(Mg + (size_t)(dir * 64 + lane) * 128 + 32 * wv);
#pragma unroll
        for (int k = 0; k < 16; ++k) Mres[k] = (v2f){mr2[k].x, mr2[k].y};
    }

    // ---- my measurement assignment: 3 wires, Z or X ----
    const int w0  = (wv & 1) * 3;            // wire base
    const int isX = wv >> 1;                 // waves 2,3 do <X>
    int zmask3[3], bpa3[3];
#pragma unroll
    for (int k = 0; k < 3; ++k) {
        const int w = w0 + k;
        zmask3[k] = ((lane >> (5 - w)) & 1) << 31;
        bpa3[k]   = (lane ^ (1 << (5 - w))) << 2;
    }
    const int ow0 = wv ^ 1, ow1 = wv ^ 2, ow2 = wv ^ 3;   // other waves

    // ---- flag rendezvous helpers ----
    auto post = [&](int* f, int val) {
        if (lane == 0)
            __hip_atomic_store(&f[wv], val, __ATOMIC_RELEASE,
                               __HIP_MEMORY_SCOPE_WORKGROUP);
    };
    auto waitf = [&](int* f, int val) {
        while (__hip_atomic_load(&f[ow0], __ATOMIC_ACQUIRE,
                                 __HIP_MEMORY_SCOPE_WORKGROUP) < val) {}
        while (__hip_atomic_load(&f[ow1], __ATOMIC_ACQUIRE,
                                 __HIP_MEMORY_SCOPE_WORKGROUP) < val) {}
        while (__hip_atomic_load(&f[ow2], __ATOMIC_ACQUIRE,
                                 __HIP_MEMORY_SCOPE_WORKGROUP) < val) {}
    };

    float h[6] = {0.f, 0.f, 0.f, 0.f, 0.f, 0.f};

    // encode h -> my 16-col matvec partial (registers only)
    auto encode_matvec = [&](v2f& acc) {
        float cw6[6], sw6[6];
#pragma unroll
        for (int w = 0; w < 6; ++w) sincos_half(h[w], sw6[w], cw6[w]);
        const float t0 = (wv & 2) ? sw6[0] : cw6[0];   // wire0 bit = wv>>1
        const float t1 = (wv & 1) ? sw6[1] : cw6[1];   // wire1 bit = wv&1
        const float A  = t0 * t1;
        float GH[4], GL[4];
        GH[0] = cw6[2] * cw6[3]; GH[1] = cw6[2] * sw6[3];
        GH[2] = sw6[2] * cw6[3]; GH[3] = sw6[2] * sw6[3];
#pragma unroll
        for (int a = 0; a < 4; ++a) GH[a] *= A;
        GL[0] = cw6[4] * cw6[5]; GL[1] = cw6[4] * sw6[5];
        GL[2] = sw6[4] * cw6[5]; GL[3] = sw6[4] * sw6[5];
        v2f y = {0.f, 0.f};
#pragma unroll
        for (int a = 0; a < 4; ++a) {
            v2f T = {0.f, 0.f};
#pragma unroll
            for (int b2 = 0; b2 < 4; ++b2)
                T = pkfma(GL[b2], Mres[4 * a + b2], T);
            y = pkfma(GH[a], T, y);
        }
        acc = y;
    };

    // walking pointers
    const float* cp = cl + (dir ? (SEQ - 1) * 12 : 0);
    const int   cstep = dir ? -12 : 12;
    float*       zp = zb + (dir ? (SEQ - 1) * NW : 0);
    const int   zstep = dir ? -NW : NW;

    __syncthreads();                         // staging + flag init visible

    // ---- peel: partial for the t=0 state (h = 0); publish epoch 0 ----
    v2f myacc;
    encode_matvec(myacc);
    pY[0][wv][lane] = (float2){myacc.x, myacc.y};
    post(fA, 0);

    for (int t = 0; t < SEQ; ++t) {
        const int buf = t & 1;

        waitf(fA, t);                        // rendezvous A (was s_barrier)

        // one batched LDS window: 3 partner partials + this step's cos/sin
        const float2 yA = pY[buf][ow0][lane];
        const float2 yB = pY[buf][ow1][lane];
        const float2 yC = pY[buf][ow2][lane];
        const float4 xq0 = ((const float4*)cp)[0];
        const float4 xq1 = ((const float4*)cp)[1];
        const float4 xq2 = ((const float4*)cp)[2];
        cp += cstep;

        const float yr = (myacc.x + yA.x) + (yB.x + yC.x);
        const float yi = (myacc.y + yA.y) + (yB.y + yC.y);

        // my 3 reductions (wave-uniform branch)
        float v3[3];
        if (isX) {
            float pr[3], pi[3];
#pragma unroll
            for (int k = 0; k < 3; ++k)
                pr[k] = __int_as_float(
                    __builtin_amdgcn_ds_bpermute(bpa3[k], __float_as_int(yr)));
#pragma unroll
            for (int k = 0; k < 3; ++k)
                pi[k] = __int_as_float(
                    __builtin_amdgcn_ds_bpermute(bpa3[k], __float_as_int(yi)));
#pragma unroll
            for (int k = 0; k < 3; ++k) v3[k] = yr * pr[k] + yi * pi[k];
        } else {
            const float q = yr * yr + yi * yi;
#pragma unroll
            for (int k = 0; k < 3; ++k)
                v3[k] = __int_as_float(__float_as_int(q) ^ zmask3[k]);
        }
        red_stage3<0x111>(v3);   // row_shr:1
        red_stage3<0x112>(v3);   // row_shr:2
        red_stage3<0x114>(v3);   // row_shr:4
        red_stage3<0x118>(v3);   // row_shr:8
        red_stage3<0x142>(v3);   // row_bcast:15
        red_stage3<0x143>(v3);   // row_bcast:31

        if (lane == 63) {
            mR[wv * 3 + 0] = v3[0];
            mR[wv * 3 + 1] = v3[1];
            mR[wv * 3 + 2] = v3[2];
        }
        post(fB, t);
        waitf(fB, t);                        // rendezvous B (was s_barrier)

        const float4 m0 = ((const float4*)mR)[0];   // Z0 Z1 Z2 Z3
        const float4 m1 = ((const float4*)mR)[1];   // Z4 Z5 X0 X1
        const float4 m2 = ((const float4*)mR)[2];   // X2 X3 X4 X5

        float z[6];
        z[0] = xq0.x * m0.x - xq0.y * m1.z;
        z[1] = xq0.z * m0.y - xq0.w * m1.w;
        z[2] = xq1.x * m0.z - xq1.y * m2.x;
        z[3] = xq1.z * m0.w - xq1.w * m2.y;
        z[4] = xq2.x * m1.x - xq2.y * m2.z;
        z[5] = xq2.z * m1.y - xq2.w * m2.w;

        if (tid == 63) {                     // one lane buffers outputs
#pragma unroll
            for (int w = 0; w < 6; ++w) zp[w] = z[w];
        }
        zp += zstep;
#pragma unroll
        for (int w = 0; w < 6; ++w) h[w] = z[w];   // h stays in VGPRs

        // next state's partial into the other buffer; publish epoch t+1
        encode_matvec(myacc);
        pY[buf ^ 1][wv][lane] = (float2){myacc.x, myacc.y};
        post(fA, t + 1);
    }
    __syncthreads();                         // order zb writes vs bulk read

    // ---- bulk store outputs: 768 float4 over 256 threads ----
    {
        const float4* zs4 = (const float4*)zb;
        float4* go = (float4*)orow;
#pragma unroll
        for (int k = 0; k < 3; ++k) {
            const int idx = tid + k * 256;
            go[idx] = zs4[idx];
        }
    }
}

// ---------------------------------------------------------------------------
// Kernel 3: out = sigmoid(fc)*h_fwd + sigmoid(bc)*h_bwd, dtype per flag.
// ---------------------------------------------------------------------------
__global__ void k_combine(const float* __restrict__ hbuf,
                          const float* __restrict__ misc,
                          void* __restrict__ out, const int* __restrict__ flag) {
    const int i = blockIdx.x * blockDim.x + threadIdx.x;
    if (i >= NELEM) return;
    const float sf = 1.f / (1.f + __expf(-misc[76]));
    const float sb = 1.f / (1.f + __expf(-misc[77]));
    const float v = sf * hbuf[i] + sb * hbuf[NELEM + i];
    if (*flag) ((__hip_bfloat16*)out)[i] = __float2bfloat16(v);
    else       ((float*)out)[i] = v;
}

// ---------------------------------------------------------------------------
extern "C" void kernel_launch(void* const* d_in, const int* in_sizes, int n_in,
                              void* d_out, int out_size, void* d_ws, size_t ws_size,
                              hipStream_t stream) {
    const void* ang  = d_in[0];
    const void* poly = d_in[1];
    const void* fp   = d_in[2];
    const void* bp   = d_in[3];
    const void* fc   = d_in[4];
    const void* bc   = d_in[5];

    // ws (floats): pad[32] | cs[2*NELEM] | misc[128] | hbuf[2*NELEM] |
    //              Mg[16384] | flag
    float* cs   = (float*)d_ws + 32;
    float* misc = cs + 2 * NELEM;
    float* hbuf = misc + 128;
    float* Mg   = hbuf + 2 * NELEM;
    int*   flag = (int*)(Mg + 2 * 64 * 64 * 2);

    k_prep<<<NCONV + 32, 256, 0, stream>>>(ang, poly, fp, bp, fc, bc,
                                           cs, misc, Mg, flag);
    k_sim<<<256, 256, 0, stream>>>(cs, Mg, hbuf);
    k_combine<<<(NELEM + 255) / 256, 256, 0, stream>>>(hbuf, misc, d_out, flag);
}

// Round 18
// 345.293 us; speedup vs baseline: 1.3665x; 1.3665x over previous
//
#include <hip/hip_runtime.h>
#include <hip/hip_bf16.h>
#include <stdint.h>

#define BATCH 128
#define SEQ   512
#define NW    6
#define DIM   64
#define NELEM (BATCH * SEQ * NW)   // 393216
#define PI_F  3.14159265358979323846f
#define NCONV 1536                 // convert blocks; msetup blocks follow

typedef float v2f __attribute__((ext_vector_type(2)));

__device__ __forceinline__ v2f pkfma(float s, v2f m, v2f a) {
    return __builtin_elementwise_fma((v2f){s, s}, m, a);
}

// ---------------------------------------------------------------------------
// Interleaved 3-way DPP wave-64 reduction stage. After shr1,2,4,8 +
// bcast15,31 the totals land in lane 63.
// ---------------------------------------------------------------------------
template <int CTRL>
__device__ __forceinline__ void red_stage3(float v[3]) {
#pragma unroll
    for (int k = 0; k < 3; ++k)
        v[k] += __int_as_float(__builtin_amdgcn_update_dpp(
            0, __float_as_int(v[k]), CTRL, 0xF, 0xF, false));
}

// Branch-free sincos(h/2), |h| <= 1. Trimmed to the bf16-output tolerance:
// cos err <= 2.2e-5, sin err <= 1.6e-6 (threshold 2.4e-2, output bf16).
__device__ __forceinline__ void sincos_half(float h, float& s, float& c) {
    const float u = h * h;
    c = fmaf(u, fmaf(u, 2.6041667e-3f, -0.125f), 1.0f);
    s = h * fmaf(u, fmaf(u, 2.6041667e-4f, -2.0833333e-2f), 0.5f);
}

__device__ __forceinline__ float ldf(const void* p, int i, bool bf) {
    if (bf) {
        uint32_t u = (uint32_t)((const uint16_t*)p)[i];
        return __uint_as_float(u << 16);
    }
    return ((const float*)p)[i];
}

// ---------------------------------------------------------------------------
// Kernel 1 (fused detect + convert + msetup):
//  - every block self-detects bf16-vs-f32 from the first 256 words of angles
//  - blocks [0,NCONV): cs[i] = {cos,sin}(x_i); misc fills; block0 posts flag
//  - blocks [NCONV, NCONV+32): 4 waves/block evolve one (dir,col) basis
//    column each -> Mg  (params read directly from d_in, no dependency)
// ---------------------------------------------------------------------------
__global__ void k_prep(const void* ang, const void* poly, const void* fp,
                       const void* bp, const void* fc, const void* bc,
                       float* __restrict__ cs, float* __restrict__ misc,
                       float* __restrict__ Mg, int* __restrict__ flag) {
    __shared__ int cnt;
    if (threadIdx.x == 0) cnt = 0;
    __syncthreads();
    {
        uint32_t w = ((const uint32_t*)ang)[threadIdx.x & 255];
        uint32_t e = (w >> 8) & 0xFFu;
        if (e >= 0x3Au && e <= 0x41u) atomicAdd(&cnt, 1);
    }
    __syncthreads();
    const bool bf = (cnt >= 128);

    if (blockIdx.x < NCONV) {
        const int i = blockIdx.x * 256 + threadIdx.x;
        if (i < NELEM) {
            float x = ldf(ang, i, bf);
            float s, c;
            __sincosf(x, &s, &c);
            cs[2 * i]     = c;
            cs[2 * i + 1] = s;
        }
        if (i == 200)      misc[76] = ldf(fc, 0, bf);
        else if (i == 201) misc[77] = ldf(bc, 0, bf);
        else if (i == 202) *flag = bf ? 1 : 0;
        return;
    }

    // ---- msetup path: 4 columns per block (one per wave) ----
    const int lane = threadIdx.x & 63;
    const int tix  = (blockIdx.x - NCONV) * 4 + (threadIdx.x >> 6);
    const int dir  = tix >> 6;
    const int col  = tix & 63;
    const void* prm = dir ? bp : fp;
    const int p = lane;

    float yr = (p == col) ? 1.f : 0.f;
    float yi = 0.f;

#pragma unroll
    for (int d = 0; d < 4; ++d) {
        const float th = 0.5f * PI_F * ldf(poly, d, bf) *
                         (float)(6 - 2 * (int)__popc((unsigned)p));
        float s, c;
        __sincosf(th, &s, &c);
        const float nr = yr * c + yi * s;
        const float ni = yi * c - yr * s;
        yr = nr; yi = ni;
#pragma unroll
        for (int k = 0; k < 6; ++k) {
            const int cw = k, tw = (k + 1) % 6;
            const int src = p ^ (((p >> (5 - cw)) & 1) << (5 - tw));
            yr = __shfl(yr, src, 64);
            yi = __shfl(yi, src, 64);
        }
    }

    int idx = 0;
#pragma unroll
    for (int l = 0; l < 2; ++l) {
#pragma unroll
        for (int w = 0; w < 6; ++w) {
            float cx, sx, cy, sy, cz, sz;
            __sincosf(0.5f * ldf(prm, idx + 0, bf), &sx, &cx);
            __sincosf(0.5f * ldf(prm, idx + 1, bf), &sy, &cy);
            __sincosf(0.5f * ldf(prm, idx + 2, bf), &sz, &cz);
            idx += 3;
            const float A = cy * cx, B = sy * sx, C = sy * cx, D = cy * sx;
            const float U00r = cz * A + sz * B, U00i = cz * B - sz * A;
            const float U11r = U00r,            U11i = sz * A - cz * B;
            const float Xr   = cz * C + sz * D, Xi   = sz * C - cz * D;
            const int m  = 1 << (5 - w);
            const int bb = (p >> (5 - w)) & 1;
            const float C1r = bb ? U11r : U00r;
            const float C1i = bb ? U11i : U00i;
            const float C2r = bb ? Xr : -Xr;
            const float C2i = Xi;
            const float pr = __shfl_xor(yr, m, 64);
            const float pi = __shfl_xor(yi, m, 64);
            const float nr = C1r * yr - C1i * yi + C2r * pr - C2i * pi;
            const float ni = C1r * yi + C1i * yr + C2r * pi + C2i * pr;
            yr = nr; yi = ni;
        }
#pragma unroll
        for (int k = 0; k < 5; ++k) {
            const int src = p ^ (((p >> (5 - k)) & 1) << (5 - (k + 1)));
            yr = __shfl(yr, src, 64);
            yi = __shfl(yi, src, 64);
        }
    }

    float* out = Mg + ((size_t)(dir * 64 + p) * 64 + (size_t)col) * 2;
    out[0] = yr;
    out[1] = yi;
}

// ---------------------------------------------------------------------------
// Kernel 2: recurrent sim — r12 structure (4 waves, split measurement, two
// s_barriers) with micro-opts:
//  - xq cos/sin reads hoisted into the pY-read LDS window (they were on the
//    post-barrier-B critical path; they depend on nothing in-loop)
//  - own matvec partial kept in registers (3 pY reads, not 4)
//  - trimmed sincos polynomials
// ---------------------------------------------------------------------------
__global__ void __launch_bounds__(256, 1) k_sim(const float* __restrict__ cs,
                                                const float* __restrict__ Mg,
                                                float* __restrict__ hbuf) {
    const int tid   = threadIdx.x;
    const int lane  = tid & 63;
    const int wv    = tid >> 6;              // wave 0..3
    const int chain = blockIdx.x;            // 0..255
    const int dir   = chain >> 7;
    const int b     = chain & 127;
    float* orow = hbuf + (size_t)dir * NELEM + (size_t)b * (SEQ * NW);
    const float* csrow = cs + (size_t)b * (SEQ * NW * 2);

    __shared__ __align__(16) float  cl[SEQ * 12];   // 24 KB staged cos/sin(x)
    __shared__ __align__(16) float  zb[SEQ * NW];   // 12 KB output buffer
    __shared__ float2 pY[2][4][DIM];                // ping-pong partials, 4 KB
    __shared__ __align__(16) float  mR[12];         // measure-sum slab

    // ---- stage this chain's cos/sin rows into LDS (once) ----
    {
        const float4* src = (const float4*)csrow;   // 1536 float4
        float4* dst = (float4*)cl;
#pragma unroll
        for (int k = 0; k < 6; ++k) {
            const int idx = tid + k * 256;
            dst[idx] = src[idx];
        }
    }

    // ---- my 16 resident M columns: row = lane, cols = 16wv..16wv+15 ----
    v2f Mres[16];
    {
        const float2* mr2 =
            (const float2*)(Mg + (size_t)(dir * 64 + lane) * 128 + 32 * wv);
#pragma unroll
        for (int k = 0; k < 16; ++k) Mres[k] = (v2f){mr2[k].x, mr2[k].y};
    }

    // ---- my measurement assignment: 3 wires, Z or X ----
    const int w0  = (wv & 1) * 3;            // wire base
    const int isX = wv >> 1;                 // waves 2,3 do <X>
    int zmask3[3], bpa3[3];
#pragma unroll
    for (int k = 0; k < 3; ++k) {
        const int w = w0 + k;
        zmask3[k] = ((lane >> (5 - w)) & 1) << 31;
        bpa3[k]   = (lane ^ (1 << (5 - w))) << 2;
    }
    const int ow0 = wv ^ 1, ow1 = wv ^ 2, ow2 = wv ^ 3;   // other waves

    float h[6] = {0.f, 0.f, 0.f, 0.f, 0.f, 0.f};

    // encode h -> my 16-col matvec partial (registers only)
    auto encode_matvec = [&](v2f& acc) {
        float cw6[6], sw6[6];
#pragma unroll
        for (int w = 0; w < 6; ++w) sincos_half(h[w], sw6[w], cw6[w]);
        const float t0 = (wv & 2) ? sw6[0] : cw6[0];   // wire0 bit = wv>>1
        const float t1 = (wv & 1) ? sw6[1] : cw6[1];   // wire1 bit = wv&1
        const float A  = t0 * t1;
        float GH[4], GL[4];
        GH[0] = cw6[2] * cw6[3]; GH[1] = cw6[2] * sw6[3];
        GH[2] = sw6[2] * cw6[3]; GH[3] = sw6[2] * sw6[3];
#pragma unroll
        for (int a = 0; a < 4; ++a) GH[a] *= A;
        GL[0] = cw6[4] * cw6[5]; GL[1] = cw6[4] * sw6[5];
        GL[2] = sw6[4] * cw6[5]; GL[3] = sw6[4] * sw6[5];
        v2f y = {0.f, 0.f};
#pragma unroll
        for (int a = 0; a < 4; ++a) {
            v2f T = {0.f, 0.f};
#pragma unroll
            for (int b2 = 0; b2 < 4; ++b2)
                T = pkfma(GL[b2], Mres[4 * a + b2], T);
            y = pkfma(GH[a], T, y);
        }
        acc = y;
    };

    // walking pointers
    const float* cp = cl + (dir ? (SEQ - 1) * 12 : 0);
    const int   cstep = dir ? -12 : 12;
    float*       zp = zb + (dir ? (SEQ - 1) * NW : 0);
    const int   zstep = dir ? -NW : NW;

    __syncthreads();                         // staging + Mres visible

    // ---- peel: partial for the t=0 state (h = 0) ----
    v2f myacc;
    encode_matvec(myacc);
    pY[0][wv][lane] = (float2){myacc.x, myacc.y};
    __syncthreads();                         // barrier A

    for (int t = 0; t < SEQ; ++t) {
        const int buf = t & 1;

        // one batched LDS window: 3 partner partials + this step's cos/sin
        // (xq hoisted off the post-barrier-B critical path)
        const float2 yA = pY[buf][ow0][lane];
        const float2 yB = pY[buf][ow1][lane];
        const float2 yC = pY[buf][ow2][lane];
        const float4 xq0 = ((const float4*)cp)[0];
        const float4 xq1 = ((const float4*)cp)[1];
        const float4 xq2 = ((const float4*)cp)[2];
        cp += cstep;

        const float yr = (myacc.x + yA.x) + (yB.x + yC.x);
        const float yi = (myacc.y + yA.y) + (yB.y + yC.y);

        // my 3 reductions (wave-uniform branch)
        float v3[3];
        if (isX) {
            float pr[3], pi[3];
#pragma unroll
            for (int k = 0; k < 3; ++k)
                pr[k] = __int_as_float(
                    __builtin_amdgcn_ds_bpermute(bpa3[k], __float_as_int(yr)));
#pragma unroll
            for (int k = 0; k < 3; ++k)
                pi[k] = __int_as_float(
                    __builtin_amdgcn_ds_bpermute(bpa3[k], __float_as_int(yi)));
#pragma unroll
            for (int k = 0; k < 3; ++k) v3[k] = yr * pr[k] + yi * pi[k];
        } else {
            const float q = yr * yr + yi * yi;
#pragma unroll
            for (int k = 0; k < 3; ++k)
                v3[k] = __int_as_float(__float_as_int(q) ^ zmask3[k]);
        }
        red_stage3<0x111>(v3);   // row_shr:1
        red_stage3<0x112>(v3);   // row_shr:2
        red_stage3<0x114>(v3);   // row_shr:4
        red_stage3<0x118>(v3);   // row_shr:8
        red_stage3<0x142>(v3);   // row_bcast:15
        red_stage3<0x143>(v3);   // row_bcast:31

        if (lane == 63) {
            mR[wv * 3 + 0] = v3[0];
            mR[wv * 3 + 1] = v3[1];
            mR[wv * 3 + 2] = v3[2];
        }
        __syncthreads();                     // barrier B

        // slab read is now the only post-B LDS dependency
        const float4 m0 = ((const float4*)mR)[0];   // Z0 Z1 Z2 Z3
        const float4 m1 = ((const float4*)mR)[1];   // Z4 Z5 X0 X1
        const float4 m2 = ((const float4*)mR)[2];   // X2 X3 X4 X5

        float z[6];
        z[0] = xq0.x * m0.x - xq0.y * m1.z;
        z[1] = xq0.z * m0.y - xq0.w * m1.w;
        z[2] = xq1.x * m0.z - xq1.y * m2.x;
        z[3] = xq1.z * m0.w - xq1.w * m2.y;
        z[4] = xq2.x * m1.x - xq2.y * m2.z;
        z[5] = xq2.z * m1.y - xq2.w * m2.w;

        if (tid == 63) {                     // one lane buffers outputs
#pragma unroll
            for (int w = 0; w < 6; ++w) zp[w] = z[w];
        }
        zp += zstep;
#pragma unroll
        for (int w = 0; w < 6; ++w) h[w] = z[w];   // h stays in VGPRs

        // next state's partial into the other buffer
        encode_matvec(myacc);
        pY[buf ^ 1][wv][lane] = (float2){myacc.x, myacc.y};
        __syncthreads();                     // barrier A
    }

    // ---- bulk store outputs: 768 float4 over 256 threads ----
    {
        const float4* zs4 = (const float4*)zb;
        float4* go = (float4*)orow;
#pragma unroll
        for (int k = 0; k < 3; ++k) {
            const int idx = tid + k * 256;
            go[idx] = zs4[idx];
        }
    }
}

// ---------------------------------------------------------------------------
// Kernel 3: out = sigmoid(fc)*h_fwd + sigmoid(bc)*h_bwd, dtype per flag.
// ---------------------------------------------------------------------------
__global__ void k_combine(const float* __restrict__ hbuf,
                          const float* __restrict__ misc,
                          void* __restrict__ out, const int* __restrict__ flag) {
    const int i = blockIdx.x * blockDim.x + threadIdx.x;
    if (i >= NELEM) return;
    const float sf = 1.f / (1.f + __expf(-misc[76]));
    const float sb = 1.f / (1.f + __expf(-misc[77]));
    const float v = sf * hbuf[i] + sb * hbuf[NELEM + i];
    if (*flag) ((__hip_bfloat16*)out)[i] = __float2bfloat16(v);
    else       ((float*)out)[i] = v;
}

// ---------------------------------------------------------------------------
extern "C" void kernel_launch(void* const* d_in, const int* in_sizes, int n_in,
                              void* d_out, int out_size, void* d_ws, size_t ws_size,
                              hipStream_t stream) {
    const void* ang  = d_in[0];
    const void* poly = d_in[1];
    const void* fp   = d_in[2];
    const void* bp   = d_in[3];
    const void* fc   = d_in[4];
    const void* bc   = d_in[5];

    // ws (floats): pad[32] | cs[2*NELEM] | misc[128] | hbuf[2*NELEM] |
    //              Mg[16384] | flag
    float* cs   = (float*)d_ws + 32;
    float* misc = cs + 2 * NELEM;
    float* hbuf = misc + 128;
    float* Mg   = hbuf + 2 * NELEM;
    int*   flag = (int*)(Mg + 2 * 64 * 64 * 2);

    k_prep<<<NCONV + 32, 256, 0, stream>>>(ang, poly, fp, bp, fc, bc,
                                           cs, misc, Mg, flag);
    k_sim<<<256, 256, 0, stream>>>(cs, Mg, hbuf);
    k_combine<<<(NELEM + 255) / 256, 256, 0, stream>>>(hbuf, misc, d_out, flag);
}